// Round 5
// baseline (28.559 us; speedup 1.0000x reference)
//
#include <hip/hip_runtime.h>
#include <math.h>

#define BLOCK 256
#define MAXT  64

// One thread per (b, a). 1536 blocks -> 6 blocks/CU, 24 waves/CU (75% occ).
// Division-free assignment:
//   iou = n/(d-n), n=inter, d=area_a+area_t, monotone in n/d =>
//   argmax via cross-mult n_t*d_best > n_best*d_t (strict > == first-max),
//   and max_iou > 0.5 <=> 3*n_best > d_best.
// Targets are read inside the loop through a wave-UNIFORM address from a
// const __restrict__ pointer -> scalar s_load (SGPR broadcast), so the hot
// loop has no per-t LDS b128 and no VMEM. Areas come from a 64-entry LDS
// broadcast read; boxes are staged in LDS only for the positive epilogue.
__global__ void __launch_bounds__(BLOCK)
rpn_main(const float* __restrict__ reg,
         const float* __restrict__ cls,
         const float* __restrict__ anchors,
         const float* __restrict__ targets,
         float* __restrict__ partials,   // SoA: [3][nblk]
         int A, int B, int T, int nblk) {
    const int blocksPerB = A / BLOCK;               // exact for this shape
    const int b = blockIdx.x / blocksPerB;
    const int a = (blockIdx.x - b * blocksPerB) * BLOCK + threadIdx.x;

    __shared__ float4 s_box[MAXT];    // epilogue only
    __shared__ float  s_area[MAXT];
    if (threadIdx.x < T) {
        const float4 t4 = reinterpret_cast<const float4*>(targets)[b * T + threadIdx.x];
        s_box[threadIdx.x]  = t4;
        s_area[threadIdx.x] = (t4.z - t4.x) * (t4.w - t4.y);
    }
    __syncthreads();

    const float4 A0 = reinterpret_cast<const float4*>(anchors)[a];
    const float  sa = (A0.z - A0.x) * (A0.w - A0.y);

    // hoisted cls + stable softplus (matches jax.nn.softplus)
    const int   base = b * A;
    const float c0   = cls[base + a];
    const float sp0  = fmaxf(c0, 0.f) + log1pf(expf(-fabsf(c0)));

    // wave-uniform target pointer for scalar loads in the hot loop
    const float4* __restrict__ tb4 = reinterpret_cast<const float4*>(targets) + b * T;

    float bn = 0.f, bd = 1.f;
    int   bt = 0;

    #pragma unroll 8
    for (int t = 0; t < T; ++t) {
        const float4 tb = tb4[t];        // uniform addr -> s_load_dwordx4 (SGPR)
        const float  st = s_area[t];     // ds_read_b32 broadcast
        const float iw = fmaxf(fminf(tb.z, A0.z) - fmaxf(tb.x, A0.x), 0.f);
        const float ih = fmaxf(fminf(tb.w, A0.w) - fmaxf(tb.y, A0.y), 0.f);
        const float n  = iw * ih;
        const float d  = sa + st;
        if (n * bd > bn * d) { bn = n; bd = d; bt = t; }   // first-max
    }

    const float pos = (3.f * bn > bd) ? 1.f : 0.f;
    float bce  = sp0 - c0 * pos;
    float npos = pos;
    float sl1  = 0.f;

    if (pos != 0.f) {
        const float4 r  = reinterpret_cast<const float4*>(reg)[base + a];
        const float4 tb = s_box[bt];
        float e, ae;
        e = r.x - (tb.x - A0.x); ae = fabsf(e); sl1 += (ae < 1.f) ? 0.5f * e * e : ae - 0.5f;
        e = r.y - (tb.y - A0.y); ae = fabsf(e); sl1 += (ae < 1.f) ? 0.5f * e * e : ae - 0.5f;
        e = r.z - (tb.z - A0.z); ae = fabsf(e); sl1 += (ae < 1.f) ? 0.5f * e * e : ae - 0.5f;
        e = r.w - (tb.w - A0.w); ae = fabsf(e); sl1 += (ae < 1.f) ? 0.5f * e * e : ae - 0.5f;
    }

    // deterministic block reduction: wave64 shuffle then cross-wave LDS
    for (int off = 32; off > 0; off >>= 1) {
        bce  += __shfl_down(bce,  off, 64);
        sl1  += __shfl_down(sl1,  off, 64);
        npos += __shfl_down(npos, off, 64);
    }
    __shared__ float w_bce[BLOCK / 64], w_sl1[BLOCK / 64], w_np[BLOCK / 64];
    const int lane = threadIdx.x & 63, wid = threadIdx.x >> 6;
    if (lane == 0) { w_bce[wid] = bce; w_sl1[wid] = sl1; w_np[wid] = npos; }
    __syncthreads();
    if (threadIdx.x == 0) {
        float tb_ = 0.f, ts_ = 0.f, tn_ = 0.f;
        for (int w = 0; w < BLOCK / 64; ++w) {
            tb_ += w_bce[w]; ts_ += w_sl1[w]; tn_ += w_np[w];
        }
        partials[0 * nblk + blockIdx.x] = tb_;
        partials[1 * nblk + blockIdx.x] = ts_;
        partials[2 * nblk + blockIdx.x] = tn_;
    }
}

// Final reduce: ONE wave, pure double shuffle reduction, no __syncthreads.
__global__ void __launch_bounds__(64)
rpn_final(const float* __restrict__ partials, int nblk,
          float* __restrict__ out, int BA) {
    double b = 0.0, s = 0.0, n = 0.0;
    for (int i = threadIdx.x; i < nblk; i += 64) {
        b += (double)partials[0 * nblk + i];
        s += (double)partials[1 * nblk + i];
        n += (double)partials[2 * nblk + i];
    }
    for (int off = 32; off > 0; off >>= 1) {
        b += __shfl_down(b, off, 64);
        s += __shfl_down(s, off, 64);
        n += __shfl_down(n, off, 64);
    }
    if (threadIdx.x == 0) {
        const double denom = n > 1.0 ? n : 1.0;
        const double reg_loss = (n > 0.0) ? (s / denom) : 0.0;
        out[0] = (float)(b / (double)BA);     // cls_loss (mean BCE)
        out[1] = (float)(reg_loss * 0.25);    // reg_loss / 4
    }
}

extern "C" void kernel_launch(void* const* d_in, const int* in_sizes, int n_in,
                              void* d_out, int out_size, void* d_ws, size_t ws_size,
                              hipStream_t stream) {
    const float* reg     = (const float*)d_in[0];
    const float* cls     = (const float*)d_in[1];
    const float* anchors = (const float*)d_in[2];
    const float* targets = (const float*)d_in[3];
    float* out = (float*)d_out;

    const int A = in_sizes[2] / 4;          // anchors [A,4]
    const int B = in_sizes[1] / A;          // cls [B,A]
    const int T = in_sizes[3] / (B * 4);    // targets [B,T,4]
    const int BA = B * A;
    const int nblk = BA / BLOCK;            // 1536 -> 6 blocks/CU

    float* partials = (float*)d_ws;         // SoA [3][nblk], fully overwritten every call

    rpn_main<<<nblk, BLOCK, 0, stream>>>(reg, cls, anchors, targets,
                                         partials, A, B, T, nblk);
    rpn_final<<<1, 64, 0, stream>>>(partials, nblk, out, BA);
}